// Round 10
// baseline (268.833 us; speedup 1.0000x reference)
//
#include <hip/hip_runtime.h>

#define NTOK 2048
#define DD    128
#define CHK   64
#define NPART 4
#define PCH   8      // chunks per sequence-part
#define SEL   16384  // DD*DD

typedef __attribute__((ext_vector_type(8))) short bf16x8;
typedef __attribute__((ext_vector_type(4))) float f32x4;
typedef unsigned short u16;
typedef unsigned int u32;

#define MFMA(a,b,c) __builtin_amdgcn_mfma_f32_16x16x32_bf16(a,b,c,0,0,0)

// raw barrier: LDS-visibility only; in-flight global loads stay in flight
#define SBAR() do{ __builtin_amdgcn_sched_barrier(0); \
  asm volatile("s_waitcnt lgkmcnt(0)" ::: "memory"); \
  __builtin_amdgcn_s_barrier(); \
  __builtin_amdgcn_sched_barrier(0); }while(0)

__device__ __forceinline__ u16 f2bf(float f){
  union { float f; unsigned u; } x; x.f = f;
  return (u16)((x.u + 0x7fffu + ((x.u >> 16) & 1u)) >> 16);
}
// XOR-swizzle 16B units within 128B windows by row&7
__device__ __forceinline__ int swz(int r, int c, int re){
  int b = (r*re + c)*2;
  return b ^ ((r & 7) << 4);
}
__device__ __forceinline__ void lds_w1(u16* a, int r, int c, int re, u16 v){
  *(u16*)((char*)a + swz(r,c,re)) = v;
}
__device__ __forceinline__ void lds_w4(u16* a, int r, int c, int re, ushort4 v){
  *(ushort4*)((char*)a + swz(r,c,re)) = v;
}
__device__ __forceinline__ bf16x8 lds_r8(const u16* a, int r, int c, int re){
  return *(const bf16x8*)((const char*)a + swz(r,c,re));
}
__device__ __forceinline__ void gld16(const float* g, float* l){
  __builtin_amdgcn_global_load_lds((const __attribute__((address_space(1))) u32*)g,
                                   (__attribute__((address_space(3))) u32*)l, 16, 0, 0);
}

// ========== pass 1: per (head, part): 8-chunk scan, full D=128 x E=128, 4 waves ==========
__global__ __launch_bounds__(256, 1) void gla_part(
    const float* __restrict__ Qg, const float* __restrict__ Kg,
    const float* __restrict__ Vg, const float* __restrict__ Gg,
    float* __restrict__ Og, float* __restrict__ Umid,
    float* __restrict__ Btot, float* __restrict__ Bpre)
{
  __shared__ float Kraw[CHK*DD];   // 32 KB raw K chunk (src-swizzled via gld16)
  __shared__ u16 sKh [CHK*DD];     // 16 KB  K_hat [s][d]
  __shared__ u16 sKhT[DD*CHK];     // 16 KB  K_hat^T [d][s]
  __shared__ u16 sVT [DD*CHK];     // 16 KB  V^T [e][s]  (full 128 e)
  __shared__ u16 sST [DD*DD];      // 32 KB  S^T [e][d]  (full)
  __shared__ u16 sPb [CHK*CHK];    //  8 KB  masked P [t][s]

  const int tid = threadIdx.x;
  const int w = tid >> 6, l = tid & 63, lr = l & 15, lh = l >> 4;
  const int head = blockIdx.x & 63;
  const int part = blockIdx.x >> 6;
  const int tbase = part * (PCH*CHK);

  const float* Qp = Qg + (size_t)head*NTOK*DD;
  const float* Kp = Kg + (size_t)head*NTOK*DD;
  const float* Vp = Vg + (size_t)head*NTOK*DD;
  const float* Gp = Gg + (size_t)head*NTOK;
  float* Op = Og + (size_t)head*NTOK*DD;

  f32x4 SA[8][2] = {};    // S[d-tile dt][e-tile et of wave's slice], MFMA C-layout
  float4 vst[8], qst[8];
  float gst;

  auto loadKV = [&](int c){
    const int t0 = tbase + c*CHK;
    #pragma unroll
    for (int i=0;i<8;++i){          // K chunk via gld16, source col pre-swizzled (R2)
      int u = i*256 + tid, s = u >> 5, cu = u & 31;
      int src = (cu & 24) | ((cu & 7) ^ (s & 7));
      gld16(Kp + (size_t)(t0+s)*DD + src*4, Kraw + u*4);
    }
    const float* vp = Vp + (size_t)(t0 + (tid>>2))*DD + 4*(tid&3);
    #pragma unroll
    for (int i=0;i<8;++i) vst[i] = *(const float4*)(vp + 16*i);
    const float* qp = Qp + (size_t)(t0 + w*16 + lr)*DD + lh*8;
    #pragma unroll
    for (int i=0;i<4;++i){
      qst[2*i]   = *(const float4*)(qp + 32*i);
      qst[2*i+1] = *(const float4*)(qp + 32*i + 4);
    }
    gst = Gp[t0 + l];
  };

  float cklr, cq, scc, bl63;
  auto scan = [&](){
    float li = 1.f/(1.f + expf(-gst));
    float x  = log2f(li);
    #pragma unroll
    for (int off=1; off<64; off<<=1){
      float y = __shfl_up(x, off, 64);
      if (l >= off) x += y;
    }
    bl63 = __shfl(x, 63, 64);
    scc  = exp2f(bl63);
    cq   = exp2f(__shfl(x, w*16 + lr, 64));
    cklr = exp2f(-x) * (1.f - li);       // lane l holds k-hat scale of row l
  };

  loadKV(0);
  scan();
  float bsum = 0.f;
  if (tid == 0) Bpre[head*(NPART*PCH) + part*PCH] = 0.f;

  for (int c=0; c<PCH; ++c){
    __syncthreads();   // A: drains vmcnt (Kraw + reg loads landed); prev LDS reads done

    // ---- K convert: Kraw -> sKh + sKhT (R2-verbatim read pattern) ----
    #pragma unroll
    for (int i=0;i<8;++i){
      float4 kf = *(const float4*)(Kraw + l*DD + w*32 + ((i ^ (l&7)) * 4));
      int d = w*32 + i*4;
      u16 b0=f2bf(kf.x*cklr), b1=f2bf(kf.y*cklr), b2=f2bf(kf.z*cklr), b3=f2bf(kf.w*cklr);
      lds_w4(sKh, l, d, DD, make_ushort4(b0,b1,b2,b3));
      lds_w1(sKhT, d+0, l, CHK, b0);
      lds_w1(sKhT, d+1, l, CHK, b1);
      lds_w1(sKhT, d+2, l, CHK, b2);
      lds_w1(sKhT, d+3, l, CHK, b3);
    }
    // ---- V convert: regs -> sVT (R9 pattern, full 128 e) ----
    {
      const int srow = tid >> 2;
      #pragma unroll
      for (int i=0;i<8;++i){
        float4 vf = vst[i];
        int e = 4*((tid & 3) + 4*i);
        lds_w1(sVT, e+0, srow, CHK, f2bf(vf.x));
        lds_w1(sVT, e+1, srow, CHK, f2bf(vf.y));
        lds_w1(sVT, e+2, srow, CHK, f2bf(vf.z));
        lds_w1(sVT, e+3, srow, CHK, f2bf(vf.w));
      }
    }
    // ---- S snapshot: wave's e-slice rows [32w..32w+32) x all d ----
    #pragma unroll
    for (int dt=0;dt<8;++dt){
      const int dbase = dt*16 + lh*4;
      lds_w4(sST, 32*w + lr,      dbase, DD,
             make_ushort4(f2bf(SA[dt][0][0]), f2bf(SA[dt][0][1]), f2bf(SA[dt][0][2]), f2bf(SA[dt][0][3])));
      lds_w4(sST, 32*w + 16 + lr, dbase, DD,
             make_ushort4(f2bf(SA[dt][1][0]), f2bf(SA[dt][1][1]), f2bf(SA[dt][1][2]), f2bf(SA[dt][1][3])));
    }
    // ---- Q convert (R9 verbatim) ----
    bf16x8 qA[4];
    #pragma unroll
    for (int ks=0;ks<4;++ks){
      float4 a = qst[2*ks], b = qst[2*ks+1];
      bf16x8 t;
      t[0]=(short)f2bf(a.x*cq); t[1]=(short)f2bf(a.y*cq);
      t[2]=(short)f2bf(a.z*cq); t[3]=(short)f2bf(a.w*cq);
      t[4]=(short)f2bf(b.x*cq); t[5]=(short)f2bf(b.y*cq);
      t[6]=(short)f2bf(b.z*cq); t[7]=(short)f2bf(b.w*cq);
      qA[ks] = t;
    }
    SBAR();    // B: bf16 LDS visible
    if (c+1 < PCH) loadKV(c+1);     // issue next chunk's loads; in flight through compute

    // ---- phase 1: O1 = Qt * S^T (8 e-tiles) ; P = Qt * Kh^T (4 s-tiles) ----
    f32x4 o0={},o1={},o2={},o3={},o4={},o5={},o6={},o7={};
    f32x4 p0={},p1={},p2={},p3={};
    #pragma unroll
    for (int ks=0;ks<4;++ks){
      const int kk = ks*32 + lh*8;
      bf16x8 a = qA[ks];
      o0 = MFMA(a, lds_r8(sST, lr,      kk, DD), o0);
      o1 = MFMA(a, lds_r8(sST, 16+lr,   kk, DD), o1);
      o2 = MFMA(a, lds_r8(sST, 32+lr,   kk, DD), o2);
      o3 = MFMA(a, lds_r8(sST, 48+lr,   kk, DD), o3);
      o4 = MFMA(a, lds_r8(sST, 64+lr,   kk, DD), o4);
      o5 = MFMA(a, lds_r8(sST, 80+lr,   kk, DD), o5);
      o6 = MFMA(a, lds_r8(sST, 96+lr,   kk, DD), o6);
      o7 = MFMA(a, lds_r8(sST, 112+lr,  kk, DD), o7);
      p0 = MFMA(a, lds_r8(sKh, lr,    kk, DD), p0);
      p1 = MFMA(a, lds_r8(sKh, 16+lr, kk, DD), p1);
      p2 = MFMA(a, lds_r8(sKh, 32+lr, kk, DD), p2);
      p3 = MFMA(a, lds_r8(sKh, 48+lr, kk, DD), p3);
    }
    // ---- causal mask -> sPb (own t rows; producer == consumer per wave) ----
    {
      const int t = w*16 + lh*4;
      #pragma unroll
      for (int r=0;r<4;++r){
        int tt = t + r;
        lds_w1(sPb, tt, lr,    CHK, f2bf((lr    <= tt) ? p0[r] : 0.f));
        lds_w1(sPb, tt, 16+lr, CHK, f2bf((16+lr <= tt) ? p1[r] : 0.f));
        lds_w1(sPb, tt, 32+lr, CHK, f2bf((32+lr <= tt) ? p2[r] : 0.f));
        lds_w1(sPb, tt, 48+lr, CHK, f2bf((48+lr <= tt) ? p3[r] : 0.f));
      }
    }
    asm volatile("s_waitcnt lgkmcnt(0)" ::: "memory");
    __builtin_amdgcn_sched_barrier(0);

    // ---- phase 2: O2 += P*V (8 e-tiles) ; S += Khat^T*V (8 d-tiles x own 2 e-tiles) ----
    #pragma unroll
    for (int k2=0;k2<2;++k2){
      const int kk = k2*32 + lh*8;
      bf16x8 pa = lds_r8(sPb, w*16 + lr, kk, CHK);
      bf16x8 v0 = lds_r8(sVT, lr,      kk, CHK);
      bf16x8 v1 = lds_r8(sVT, 16+lr,   kk, CHK);
      bf16x8 v2 = lds_r8(sVT, 32+lr,   kk, CHK);
      bf16x8 v3 = lds_r8(sVT, 48+lr,   kk, CHK);
      bf16x8 v4 = lds_r8(sVT, 64+lr,   kk, CHK);
      bf16x8 v5 = lds_r8(sVT, 80+lr,   kk, CHK);
      bf16x8 v6 = lds_r8(sVT, 96+lr,   kk, CHK);
      bf16x8 v7 = lds_r8(sVT, 112+lr,  kk, CHK);
      o0 = MFMA(pa, v0, o0); o1 = MFMA(pa, v1, o1);
      o2 = MFMA(pa, v2, o2); o3 = MFMA(pa, v3, o3);
      o4 = MFMA(pa, v4, o4); o5 = MFMA(pa, v5, o5);
      o6 = MFMA(pa, v6, o6); o7 = MFMA(pa, v7, o7);
      // own e-slice B operands (runtime row addr, compile-time reg indices)
      bf16x8 ve0 = lds_r8(sVT, 32*w + lr,      kk, CHK);
      bf16x8 ve1 = lds_r8(sVT, 32*w + 16 + lr, kk, CHK);
      #pragma unroll
      for (int dt=0;dt<8;++dt){
        bf16x8 ka = lds_r8(sKhT, dt*16 + lr, kk, CHK);
        SA[dt][0] = MFMA(ka, ve0, SA[dt][0]);
        SA[dt][1] = MFMA(ka, ve1, SA[dt][1]);
      }
    }
    #pragma unroll
    for (int dt=0;dt<8;++dt)
      #pragma unroll
      for (int r=0;r<4;++r){ SA[dt][0][r] *= scc; SA[dt][1][r] *= scc; }

    // ---- write O chunk (fp32), own t rows, all 128 e ----
    {
      float* op = Op + (size_t)(tbase + c*CHK + w*16 + lh*4)*DD;
      #pragma unroll
      for (int r=0;r<4;++r){
        op[r*DD + lr]       = o0[r];
        op[r*DD + 16 + lr]  = o1[r];
        op[r*DD + 32 + lr]  = o2[r];
        op[r*DD + 48 + lr]  = o3[r];
        op[r*DD + 64 + lr]  = o4[r];
        op[r*DD + 80 + lr]  = o5[r];
        op[r*DD + 96 + lr]  = o6[r];
        op[r*DD + 112 + lr] = o7[r];
      }
    }
    // ---- tail: bookkeeping + next-chunk scan (gst already holds c+1) ----
    if (c+1 < PCH){
      bsum += bl63;
      if (tid == 0) Bpre[head*(NPART*PCH) + part*PCH + c + 1] = bsum;
      scan();
    }
  }
  bsum += bl63;

  if (part < 3){   // per-part standalone end-state, [d][e] fp32 (gla_fix layout)
    float* sm = Umid + ((size_t)head*3 + part)*SEL;
    #pragma unroll
    for (int dt=0;dt<8;++dt)
      #pragma unroll
      for (int et=0;et<2;++et)
        #pragma unroll
        for (int r=0;r<4;++r)
          sm[(size_t)(dt*16 + lh*4 + r)*DD + 32*w + et*16 + lr] = SA[dt][et][r];
  }
  if ((part == 1 || part == 2) && tid == 0)
    Btot[head*NPART + part] = bsum;
}

// ========== pass 2: O[parts 1..3] += 2^{b} Q · S_in (combine in staging; R9 verbatim) ==========
__global__ __launch_bounds__(256) void gla_fix(
    const float* __restrict__ Qg, const float* __restrict__ Gg,
    float* __restrict__ Og, const float* __restrict__ Umid,
    const float* __restrict__ Btot, const float* __restrict__ Bpre)
{
  __shared__ u16 sS[DD*DD];     // S_in^T [e][d] bf16, 32 KB
  const int tid = threadIdx.x;
  const int w = tid >> 6, l = tid & 63, lr = l & 15, lh = l >> 4;
  const int head = blockIdx.x & 63, ci = blockIdx.x >> 6;   // ci 0..23
  const int p = 1 + (ci >> 3), cwp = ci & 7;
  const int t0 = p*(PCH*CHK) + cwp*CHK;

  { // stage S_in^T with on-the-fly part combine: s=u0; p>=2: s=a1*s+u1; p==3: s=a2*s+u2
    const int d = tid >> 1, eb = (tid & 1)*64;
    const float* u0 = Umid + (size_t)head*3*SEL + (size_t)d*DD + eb;
    const float a1 = exp2f(Btot[head*NPART + 1]);
    const float a2 = exp2f(Btot[head*NPART + 2]);
    #pragma unroll
    for (int j=0;j<16;++j){
      float4 s = *(const float4*)(u0 + 4*j);
      if (p >= 2){
        float4 u1 = *(const float4*)(u0 + SEL + 4*j);
        s.x = fmaf(a1, s.x, u1.x); s.y = fmaf(a1, s.y, u1.y);
        s.z = fmaf(a1, s.z, u1.z); s.w = fmaf(a1, s.w, u1.w);
      }
      if (p == 3){
        float4 u2 = *(const float4*)(u0 + 2*SEL + 4*j);
        s.x = fmaf(a2, s.x, u2.x); s.y = fmaf(a2, s.y, u2.y);
        s.z = fmaf(a2, s.z, u2.z); s.w = fmaf(a2, s.w, u2.w);
      }
      lds_w1(sS, eb + 4*j + 0, d, DD, f2bf(s.x));
      lds_w1(sS, eb + 4*j + 1, d, DD, f2bf(s.y));
      lds_w1(sS, eb + 4*j + 2, d, DD, f2bf(s.z));
      lds_w1(sS, eb + 4*j + 3, d, DD, f2bf(s.w));
    }
  }
  // gate scan (within chunk) + part-prefix
  float gst = Gg[(size_t)head*NTOK + t0 + l];
  float li = 1.f/(1.f + expf(-gst));
  float x  = log2f(li);
  #pragma unroll
  for (int off=1; off<64; off<<=1){
    float y = __shfl_up(x, off, 64);
    if (l >= off) x += y;
  }
  const float cq = exp2f(__shfl(x, w*16 + lr, 64) + Bpre[head*(NPART*PCH) + p*PCH + cwp]);

  bf16x8 qA[4];
  const float* qp = Qg + (size_t)head*NTOK*DD + (size_t)(t0 + w*16 + lr)*DD + lh*8;
  #pragma unroll
  for (int ks=0;ks<4;++ks){
    float4 a = *(const float4*)(qp + ks*32);
    float4 b = *(const float4*)(qp + ks*32 + 4);
    bf16x8 t;
    t[0]=(short)f2bf(a.x*cq); t[1]=(short)f2bf(a.y*cq);
    t[2]=(short)f2bf(a.z*cq); t[3]=(short)f2bf(a.w*cq);
    t[4]=(short)f2bf(b.x*cq); t[5]=(short)f2bf(b.y*cq);
    t[6]=(short)f2bf(b.z*cq); t[7]=(short)f2bf(b.w*cq);
    qA[ks] = t;
  }
  __syncthreads();

  f32x4 o0={},o1={},o2={},o3={},o4={},o5={},o6={},o7={};
  #pragma unroll
  for (int ks=0;ks<4;++ks){
    const int kk = ks*32 + lh*8;
    bf16x8 a = qA[ks];
    o0 = MFMA(a, lds_r8(sS, lr,      kk, DD), o0);
    o1 = MFMA(a, lds_r8(sS, 16+lr,   kk, DD), o1);
    o2 = MFMA(a, lds_r8(sS, 32+lr,   kk, DD), o2);
    o3 = MFMA(a, lds_r8(sS, 48+lr,   kk, DD), o3);
    o4 = MFMA(a, lds_r8(sS, 64+lr,   kk, DD), o4);
    o5 = MFMA(a, lds_r8(sS, 80+lr,   kk, DD), o5);
    o6 = MFMA(a, lds_r8(sS, 96+lr,   kk, DD), o6);
    o7 = MFMA(a, lds_r8(sS, 112+lr,  kk, DD), o7);
  }
  float* op = Og + (size_t)head*NTOK*DD + (size_t)(t0 + w*16 + lh*4)*DD;
  #pragma unroll
  for (int r=0;r<4;++r){
    op[r*DD + lr]       += o0[r];
    op[r*DD + 16 + lr]  += o1[r];
    op[r*DD + 32 + lr]  += o2[r];
    op[r*DD + 48 + lr]  += o3[r];
    op[r*DD + 64 + lr]  += o4[r];
    op[r*DD + 80 + lr]  += o5[r];
    op[r*DD + 96 + lr]  += o6[r];
    op[r*DD + 112 + lr] += o7[r];
  }
}

extern "C" void kernel_launch(void* const* d_in, const int* in_sizes, int n_in,
                              void* d_out, int out_size, void* d_ws, size_t ws_size,
                              hipStream_t stream)
{
  const float* q = (const float*)d_in[0];
  const float* k = (const float*)d_in[1];
  const float* v = (const float*)d_in[2];
  const float* g = (const float*)d_in[3];
  float* out = (float*)d_out;

  char* ws = (char*)d_ws;
  float* Umid = (float*)ws;                          // 64*3*16384*4 = 12,582,912 B
  float* Btot = (float*)(ws + 12582912);             // 64*4*4 = 1 KB
  float* Bpre = (float*)(ws + 12583936);             // 64*32*4 = 8 KB

  gla_part<<<dim3(256),  dim3(256), 0, stream>>>(q, k, v, g, out, Umid, Btot, Bpre);
  gla_fix <<<dim3(1536), dim3(256), 0, stream>>>(q, g, out, Umid, Btot, Bpre);
}